// Round 2
// baseline (308.252 us; speedup 1.0000x reference)
//
#include <hip/hip_runtime.h>

// ---------------------------------------------------------------------------
// Fused attention block, bf16 MFMA pipeline.
// ws layout (needs 40 MB):
//   [0,8M)    xb   : x as bf16 [4096][1024]   (reused as Ob after gemm_qkv)
//   [8M,14M)  WqT  : W_qkv^T bf16 [3072][1024]
//   [14M,16M) WpT  : W_proj^T bf16 [1024][1024]
//   [16M,24M) Qb   : [32][2048][64] bf16  (pre-scaled by SCALE*log2e)
//   [24M,32M) Kb   : [32][2048][64] bf16
//   [32M,40M) Vt   : [32][64][2048] bf16 (V transposed per head)
// ---------------------------------------------------------------------------

typedef __bf16 bf16_t;
typedef __bf16 bf16x2 __attribute__((ext_vector_type(2)));
typedef __bf16 bf16x4 __attribute__((ext_vector_type(4)));
typedef __bf16 bf16x8 __attribute__((ext_vector_type(8)));
typedef float  f32x4  __attribute__((ext_vector_type(4)));

#define NTOK 2048
#define DIM  1024
#define NH   16
#define HD   64
#define SCL2 0.18033688011112042f   // (1/8) * log2(e), folded into Q at QKV epilogue

#define MFMA16(a, b, c) __builtin_amdgcn_mfma_f32_16x16x32_bf16((a), (b), (c), 0, 0, 0)

__device__ __forceinline__ void gload_lds16(const void* g, void* l) {
  __builtin_amdgcn_global_load_lds((const __attribute__((address_space(1))) void*)g,
                                   (__attribute__((address_space(3))) void*)l, 16, 0, 0);
}

// ---------------- fp32 -> bf16 convert (8 elems/thread) ----------------
__global__ __launch_bounds__(256) void k_cvt(const float* __restrict__ in,
                                             bf16_t* __restrict__ out) {
  int i = (blockIdx.x * 256 + threadIdx.x) * 8;
  float4 a = *(const float4*)(in + i);
  float4 b = *(const float4*)(in + i + 4);
  bf16x8 v;
  v[0] = (bf16_t)a.x; v[1] = (bf16_t)a.y; v[2] = (bf16_t)a.z; v[3] = (bf16_t)a.w;
  v[4] = (bf16_t)b.x; v[5] = (bf16_t)b.y; v[6] = (bf16_t)b.z; v[7] = (bf16_t)b.w;
  *(bf16x8*)(out + i) = v;
}

// ---------------- fp32 [rows][cols] -> bf16 [cols][rows] ----------------
__global__ __launch_bounds__(256) void k_transpose_cvt(const float* __restrict__ W,
                                                       bf16_t* __restrict__ WT,
                                                       int rows, int cols) {
  __shared__ float tile[32][33];
  int j0 = blockIdx.x * 32, i0 = blockIdx.y * 32;
  int c = threadIdx.x & 31, r0 = threadIdx.x >> 5;
#pragma unroll
  for (int it = 0; it < 4; ++it) {
    int r = r0 + it * 8;
    tile[r][c] = W[(long)(i0 + r) * cols + j0 + c];
  }
  __syncthreads();
#pragma unroll
  for (int it = 0; it < 4; ++it) {
    int r = r0 + it * 8;
    WT[(long)(j0 + r) * rows + i0 + c] = (bf16_t)tile[c][r];
  }
}

// ---------------- m97-style GEMM core: C = A * B^T ----------------
__device__ __forceinline__ void gemm_core(const bf16_t* __restrict__ A,
                                          const bf16_t* __restrict__ B,
                                          int K, int bm, int bn,
                                          bf16_t* As, bf16_t* Bs, f32x4 acc[4][4]) {
  const int t = threadIdx.x;
  const int lane = t & 63;
  const int w = t >> 6;
  const int wr = (w >> 1) * 64, wc = (w & 1) * 64;
  const int l15 = lane & 15, g = lane >> 4;
  const int srow = t >> 2, scol = (t & 3) * 8;
  const f32x4 vzero = {0.f, 0.f, 0.f, 0.f};
#pragma unroll
  for (int m = 0; m < 4; ++m)
#pragma unroll
    for (int n = 0; n < 4; ++n) acc[m][n] = vzero;

  const bf16_t* ga = A + (long)(bm + srow) * K + scol;
  const bf16_t* gb = B + (long)(bn + srow) * K + scol;
  bf16_t* lA = As + srow * 32 + scol;
  bf16_t* lB = Bs + srow * 32 + scol;
  const long rstep = 64l * K;

  for (int k0 = 0; k0 < K; k0 += 32) {
    gload_lds16(ga + k0,         lA);
    gload_lds16(ga + rstep + k0, lA + 64 * 32);
    gload_lds16(gb + k0,         lB);
    gload_lds16(gb + rstep + k0, lB + 64 * 32);
    __syncthreads();
    bf16x8 af[4], bfv[4];
#pragma unroll
    for (int m = 0; m < 4; ++m)
      af[m] = *(const bf16x8*)(As + (wr + m * 16 + l15) * 32 + g * 8);
#pragma unroll
    for (int n = 0; n < 4; ++n)
      bfv[n] = *(const bf16x8*)(Bs + (wc + n * 16 + l15) * 32 + g * 8);
#pragma unroll
    for (int m = 0; m < 4; ++m)
#pragma unroll
      for (int n = 0; n < 4; ++n)
        acc[m][n] = MFMA16(af[m], bfv[n], acc[m][n]);
    __syncthreads();
  }
}

// ---------------- GEMM1: qkv = x @ W_qkv + b, scatter to Q/K/Vt ----------------
__global__ __launch_bounds__(256) void k_gemm_qkv(const bf16_t* __restrict__ xb,
                                                  const bf16_t* __restrict__ WqT,
                                                  const float* __restrict__ bq,
                                                  bf16_t* __restrict__ Qb,
                                                  bf16_t* __restrict__ Kb,
                                                  bf16_t* __restrict__ Vt) {
  __shared__ alignas(16) bf16_t As[128 * 32];
  __shared__ alignas(16) bf16_t Bs[128 * 32];
  f32x4 acc[4][4];
  const int bm = blockIdx.y * 128, bn = blockIdx.x * 128;
  gemm_core(xb, WqT, DIM, bm, bn, As, Bs, acc);

  const int lane = threadIdx.x & 63, w = threadIdx.x >> 6;
  const int wr = (w >> 1) * 64, wc = (w & 1) * 64;
  const int l15 = lane & 15, g = lane >> 4;
#pragma unroll
  for (int n = 0; n < 4; ++n) {
    int col = bn + wc + n * 16 + l15;           // 0..3071
    float bias = bq[col];
    int t3 = col >> 10, rem = col & 1023;
    int h = rem >> 6, d = rem & 63;
#pragma unroll
    for (int m = 0; m < 4; ++m) {
      int rowb = bm + wr + m * 16 + g * 4;
#pragma unroll
      for (int r = 0; r < 4; ++r) {
        int row = rowb + r;                     // token index 0..4095
        int b = row >> 11, tok = row & 2047;
        int bh = b * NH + h;
        float val = acc[m][n][r] + bias;
        if (t3 == 0)      Qb[bh * (NTOK * HD) + tok * HD + d] = (bf16_t)(val * SCL2);
        else if (t3 == 1) Kb[bh * (NTOK * HD) + tok * HD + d] = (bf16_t)val;
        else              Vt[bh * (NTOK * HD) + d * NTOK + tok] = (bf16_t)val;
      }
    }
  }
}

// ---------------- flash attention (swapped QK^T, online softmax) ----------------
// grid = 1024 blocks (XCD-chunk-swizzled); block = 4 waves; each wave owns 16
// q-rows, streams k-tiles of 64. S^T = mfma(K, Q_scaled) so a lane holds the
// full score row for q = lane&15; per-lane online softmax (2 shuffles over g);
// P bounced through wave-private LDS into B-frags; O^T += mfma(Vt, P).
// V loads issued at tile top so L2 latency hides under S-MFMA + softmax.
__global__ __launch_bounds__(256, 4) void k_attn(const bf16_t* __restrict__ Qb,
                                                 const bf16_t* __restrict__ Kb,
                                                 const bf16_t* __restrict__ Vt,
                                                 bf16_t* __restrict__ Ob) {
  __shared__ alignas(16) bf16_t P[4][16][72];   // per-wave, padded rows (144B)
  // XCD-chunked swizzle: 128 consecutive blocks (4 heads) per XCD.
  const int b0 = blockIdx.x;
  const int swz = (b0 & 7) * 128 + (b0 >> 3);
  const int qt = swz & 31, bh = swz >> 5;       // 32 q-tiles of 64 rows per head
  const int b = bh >> 4, h = bh & 15;
  const int w = threadIdx.x >> 6, lane = threadIdx.x & 63;
  const int l15 = lane & 15, g = lane >> 4;
  const bf16_t* Qp = Qb + bh * (NTOK * HD);
  const bf16_t* Kp = Kb + bh * (NTOK * HD);
  const bf16_t* Vp = Vt + bh * (NTOK * HD);
  const int q0 = qt * 64 + w * 16;

  bf16x8 qfr[2];
#pragma unroll
  for (int kk = 0; kk < 2; ++kk)
    qfr[kk] = *(const bf16x8*)(Qp + (q0 + l15) * HD + kk * 32 + g * 8);

  const f32x4 vzero = {0.f, 0.f, 0.f, 0.f};
  f32x4 o[4];
#pragma unroll
  for (int df = 0; df < 4; ++df) o[df] = vzero;
  float m2 = -3.0e38f;
  float lsum = 0.f;

  for (int kt = 0; kt < NTOK; kt += 64) {
    // ---- issue K loads (needed now) and V loads (needed after softmax) ----
    bf16x8 ka[4][2];
#pragma unroll
    for (int kf = 0; kf < 4; ++kf) {
      const bf16_t* kr = Kp + (kt + kf * 16 + l15) * HD + g * 8;
      ka[kf][0] = *(const bf16x8*)kr;
      ka[kf][1] = *(const bf16x8*)(kr + 32);
    }
    bf16x8 va[4][2];
#pragma unroll
    for (int df = 0; df < 4; ++df) {
      const bf16_t* vr = Vp + (df * 16 + l15) * NTOK + kt + g * 8;
      va[df][0] = *(const bf16x8*)vr;
      va[df][1] = *(const bf16x8*)(vr + 32);
    }
    // ---- S^T = K * Q^T (rows = k-local, cols = q-local; already log2-scaled)
    f32x4 s[4];
#pragma unroll
    for (int kf = 0; kf < 4; ++kf) {
      s[kf] = MFMA16(ka[kf][0], qfr[0], vzero);
      s[kf] = MFMA16(ka[kf][1], qfr[1], s[kf]);
    }
    // ---- online softmax for this lane's q-row (reduce over g via shfl) ----
    float mx = -3.0e38f;
#pragma unroll
    for (int kf = 0; kf < 4; ++kf)
#pragma unroll
      for (int r = 0; r < 4; ++r) mx = fmaxf(mx, s[kf][r]);
    mx = fmaxf(mx, __shfl_xor(mx, 16));
    mx = fmaxf(mx, __shfl_xor(mx, 32));
    // defer-max (T13): only rescale when the new tile max exceeds m2 + 8
    if (__any(mx > m2 + 8.0f)) {
      float mn = fmaxf(m2, mx);
      float corr = exp2f(m2 - mn);
      m2 = mn;
      lsum *= corr;
#pragma unroll
      for (int df = 0; df < 4; ++df) o[df] *= corr;
    }
    float rs = 0.f;
#pragma unroll
    for (int kf = 0; kf < 4; ++kf) {
      float p0 = exp2f(s[kf][0] - m2);
      float p1 = exp2f(s[kf][1] - m2);
      float p2 = exp2f(s[kf][2] - m2);
      float p3 = exp2f(s[kf][3] - m2);
      rs += (p0 + p1) + (p2 + p3);
      bf16x4 pw;
      pw[0] = (bf16_t)p0; pw[1] = (bf16_t)p1; pw[2] = (bf16_t)p2; pw[3] = (bf16_t)p3;
      *(bf16x4*)&P[w][l15][kf * 16 + g * 4] = pw;
    }
    rs += __shfl_xor(rs, 16);
    rs += __shfl_xor(rs, 32);
    lsum += rs;
    // ---- O^T += Vt * P^T (wave-private P; compiler inserts lgkmcnt wait) ----
#pragma unroll
    for (int kb = 0; kb < 2; ++kb) {
      bf16x8 pf = *(const bf16x8*)&P[w][l15][kb * 32 + g * 8];
#pragma unroll
      for (int df = 0; df < 4; ++df)
        o[df] = MFMA16(va[df][kb], pf, o[df]);
    }
  }
  // ---- normalize + write O[b][tok][h*64+d] (bf16, feeds proj GEMM) ----
  float inv = 1.0f / lsum;
  int tok = q0 + l15;
  bf16_t* op = Ob + (long)(b * NTOK + tok) * DIM + h * HD;
#pragma unroll
  for (int df = 0; df < 4; ++df) {
#pragma unroll
    for (int rp = 0; rp < 2; ++rp) {
      bf16x2 v2;
      v2[0] = (bf16_t)(o[df][rp * 2]     * inv);
      v2[1] = (bf16_t)(o[df][rp * 2 + 1] * inv);
      *(bf16x2*)(op + df * 16 + g * 4 + rp * 2) = v2;
    }
  }
}

// ---------------- GEMM2: out = O @ W_proj + b (fp32 out) ----------------
__global__ __launch_bounds__(256) void k_gemm_proj(const bf16_t* __restrict__ Ob,
                                                   const bf16_t* __restrict__ WpT,
                                                   const float* __restrict__ bp,
                                                   float* __restrict__ out) {
  __shared__ alignas(16) bf16_t As[128 * 32];
  __shared__ alignas(16) bf16_t Bs[128 * 32];
  f32x4 acc[4][4];
  const int bm = blockIdx.y * 128, bn = blockIdx.x * 128;
  gemm_core(Ob, WpT, DIM, bm, bn, As, Bs, acc);

  const int lane = threadIdx.x & 63, w = threadIdx.x >> 6;
  const int wr = (w >> 1) * 64, wc = (w & 1) * 64;
  const int l15 = lane & 15, g = lane >> 4;
#pragma unroll
  for (int n = 0; n < 4; ++n) {
    int col = bn + wc + n * 16 + l15;
    float bias = bp[col];
#pragma unroll
    for (int m = 0; m < 4; ++m) {
      int rowb = bm + wr + m * 16 + g * 4;
#pragma unroll
      for (int r = 0; r < 4; ++r)
        out[(long)(rowb + r) * DIM + col] = acc[m][n][r] + bias;
    }
  }
}

// ---------------------------------------------------------------------------
extern "C" void kernel_launch(void* const* d_in, const int* in_sizes, int n_in,
                              void* d_out, int out_size, void* d_ws, size_t ws_size,
                              hipStream_t stream) {
  const float* x     = (const float*)d_in[0];
  const float* Wqkv  = (const float*)d_in[1];
  const float* bqkv  = (const float*)d_in[2];
  const float* Wproj = (const float*)d_in[3];
  const float* bproj = (const float*)d_in[4];
  float* out = (float*)d_out;

  char* ws = (char*)d_ws;
  bf16_t* xb  = (bf16_t*)(ws);                    // 8 MB
  bf16_t* WqT = (bf16_t*)(ws + (8l  << 20));      // 6 MB
  bf16_t* WpT = (bf16_t*)(ws + (14l << 20));      // 2 MB
  bf16_t* Qb  = (bf16_t*)(ws + (16l << 20));      // 8 MB
  bf16_t* Kb  = (bf16_t*)(ws + (24l << 20));      // 8 MB
  bf16_t* Vt  = (bf16_t*)(ws + (32l << 20));      // 8 MB
  bf16_t* Ob  = (bf16_t*)(ws);                    // aliases xb (x dead after gemm_qkv)

  k_cvt<<<2048, 256, 0, stream>>>(x, xb);
  k_transpose_cvt<<<dim3(96, 32), 256, 0, stream>>>(Wqkv, WqT, 1024, 3072);
  k_transpose_cvt<<<dim3(32, 32), 256, 0, stream>>>(Wproj, WpT, 1024, 1024);
  k_gemm_qkv<<<dim3(24, 32), 256, 0, stream>>>(xb, WqT, bqkv, Qb, Kb, Vt);
  k_attn<<<1024, 256, 0, stream>>>(Qb, Kb, Vt, Ob);
  k_gemm_proj<<<dim3(8, 32), 256, 0, stream>>>(Ob, WpT, bproj, out);
}

// Round 3
// 150.476 us; speedup vs baseline: 2.0485x; 2.0485x over previous
//
#include <hip/hip_runtime.h>

// ---------------------------------------------------------------------------
// Fused attention block, bf16 MFMA pipeline.
// ws layout (needs 40 MB):
//   [0,8M)    xb   : x as bf16 [4096][1024]   (reused as Ob after gemm_qkv)
//   [8M,14M)  WqT  : W_qkv^T bf16 [3072][1024]
//   [14M,16M) WpT  : W_proj^T bf16 [1024][1024]
//   [16M,24M) Qb   : [32][2048][64] bf16  (pre-scaled by SCALE*log2e)
//   [24M,32M) Kb   : [32][2048][64] bf16
//   [32M,40M) Vt   : [32][64][2048] bf16 (V transposed per head)
// ---------------------------------------------------------------------------

typedef __bf16 bf16_t;
typedef __bf16 bf16x2 __attribute__((ext_vector_type(2)));
typedef __bf16 bf16x4 __attribute__((ext_vector_type(4)));
typedef __bf16 bf16x8 __attribute__((ext_vector_type(8)));
typedef float  f32x4  __attribute__((ext_vector_type(4)));

#define NTOK 2048
#define DIM  1024
#define NH   16
#define HD   64
#define SCL2 0.18033688011112042f   // (1/8) * log2(e), folded into Q at QKV epilogue

#define MFMA16(a, b, c) __builtin_amdgcn_mfma_f32_16x16x32_bf16((a), (b), (c), 0, 0, 0)

__device__ __forceinline__ void gload_lds16(const void* g, void* l) {
  __builtin_amdgcn_global_load_lds((const __attribute__((address_space(1))) void*)g,
                                   (__attribute__((address_space(3))) void*)l, 16, 0, 0);
}

// ---------------- fp32 -> bf16 convert (8 elems/thread) ----------------
__global__ __launch_bounds__(256) void k_cvt(const float* __restrict__ in,
                                             bf16_t* __restrict__ out) {
  int i = (blockIdx.x * 256 + threadIdx.x) * 8;
  float4 a = *(const float4*)(in + i);
  float4 b = *(const float4*)(in + i + 4);
  bf16x8 v;
  v[0] = (bf16_t)a.x; v[1] = (bf16_t)a.y; v[2] = (bf16_t)a.z; v[3] = (bf16_t)a.w;
  v[4] = (bf16_t)b.x; v[5] = (bf16_t)b.y; v[6] = (bf16_t)b.z; v[7] = (bf16_t)b.w;
  *(bf16x8*)(out + i) = v;
}

// ---------------- fp32 [rows][cols] -> bf16 [cols][rows] ----------------
__global__ __launch_bounds__(256) void k_transpose_cvt(const float* __restrict__ W,
                                                       bf16_t* __restrict__ WT,
                                                       int rows, int cols) {
  __shared__ float tile[32][33];
  int j0 = blockIdx.x * 32, i0 = blockIdx.y * 32;
  int c = threadIdx.x & 31, r0 = threadIdx.x >> 5;
#pragma unroll
  for (int it = 0; it < 4; ++it) {
    int r = r0 + it * 8;
    tile[r][c] = W[(long)(i0 + r) * cols + j0 + c];
  }
  __syncthreads();
#pragma unroll
  for (int it = 0; it < 4; ++it) {
    int r = r0 + it * 8;
    WT[(long)(j0 + r) * rows + i0 + c] = (bf16_t)tile[c][r];
  }
}

// ---------------- m97-style GEMM core: C = A * B^T ----------------
__device__ __forceinline__ void gemm_core(const bf16_t* __restrict__ A,
                                          const bf16_t* __restrict__ B,
                                          int K, int bm, int bn,
                                          bf16_t* As, bf16_t* Bs, f32x4 acc[4][4]) {
  const int t = threadIdx.x;
  const int lane = t & 63;
  const int w = t >> 6;
  const int wr = (w >> 1) * 64, wc = (w & 1) * 64;
  const int l15 = lane & 15, g = lane >> 4;
  const int srow = t >> 2, scol = (t & 3) * 8;
  const f32x4 vzero = {0.f, 0.f, 0.f, 0.f};
#pragma unroll
  for (int m = 0; m < 4; ++m)
#pragma unroll
    for (int n = 0; n < 4; ++n) acc[m][n] = vzero;

  const bf16_t* ga = A + (long)(bm + srow) * K + scol;
  const bf16_t* gb = B + (long)(bn + srow) * K + scol;
  bf16_t* lA = As + srow * 32 + scol;
  bf16_t* lB = Bs + srow * 32 + scol;
  const long rstep = 64l * K;

  for (int k0 = 0; k0 < K; k0 += 32) {
    gload_lds16(ga + k0,         lA);
    gload_lds16(ga + rstep + k0, lA + 64 * 32);
    gload_lds16(gb + k0,         lB);
    gload_lds16(gb + rstep + k0, lB + 64 * 32);
    __syncthreads();
    bf16x8 af[4], bfv[4];
#pragma unroll
    for (int m = 0; m < 4; ++m)
      af[m] = *(const bf16x8*)(As + (wr + m * 16 + l15) * 32 + g * 8);
#pragma unroll
    for (int n = 0; n < 4; ++n)
      bfv[n] = *(const bf16x8*)(Bs + (wc + n * 16 + l15) * 32 + g * 8);
#pragma unroll
    for (int m = 0; m < 4; ++m)
#pragma unroll
      for (int n = 0; n < 4; ++n)
        acc[m][n] = MFMA16(af[m], bfv[n], acc[m][n]);
    __syncthreads();
  }
}

// ---------------- GEMM1: qkv = x @ W_qkv + b, scatter to Q/K/Vt ----------------
__global__ __launch_bounds__(256) void k_gemm_qkv(const bf16_t* __restrict__ xb,
                                                  const bf16_t* __restrict__ WqT,
                                                  const float* __restrict__ bq,
                                                  bf16_t* __restrict__ Qb,
                                                  bf16_t* __restrict__ Kb,
                                                  bf16_t* __restrict__ Vt) {
  __shared__ alignas(16) bf16_t As[128 * 32];
  __shared__ alignas(16) bf16_t Bs[128 * 32];
  f32x4 acc[4][4];
  const int bm = blockIdx.y * 128, bn = blockIdx.x * 128;
  gemm_core(xb, WqT, DIM, bm, bn, As, Bs, acc);

  const int lane = threadIdx.x & 63, w = threadIdx.x >> 6;
  const int wr = (w >> 1) * 64, wc = (w & 1) * 64;
  const int l15 = lane & 15, g = lane >> 4;
#pragma unroll
  for (int n = 0; n < 4; ++n) {
    int col = bn + wc + n * 16 + l15;           // 0..3071
    float bias = bq[col];
    int t3 = col >> 10, rem = col & 1023;
    int h = rem >> 6, d = rem & 63;
#pragma unroll
    for (int m = 0; m < 4; ++m) {
      int rowb = bm + wr + m * 16 + g * 4;
#pragma unroll
      for (int r = 0; r < 4; ++r) {
        int row = rowb + r;                     // token index 0..4095
        int b = row >> 11, tok = row & 2047;
        int bh = b * NH + h;
        float val = acc[m][n][r] + bias;
        if (t3 == 0)      Qb[bh * (NTOK * HD) + tok * HD + d] = (bf16_t)(val * SCL2);
        else if (t3 == 1) Kb[bh * (NTOK * HD) + tok * HD + d] = (bf16_t)val;
        else              Vt[bh * (NTOK * HD) + d * NTOK + tok] = (bf16_t)val;
      }
    }
  }
}

// ---------------- flash attention (swapped QK^T, online softmax) ----------------
// grid = 512 blocks (XCD-chunk-swizzled) x 512 threads (8 waves). Each block
// owns 128 q-rows of one head; each wave 16 q-rows. K/V tiles (64x64 bf16,
// 8KB each) are staged to LDS once per block per k-step via global_load_lds,
// double-buffered, chunk-XOR-swizzled (source-side pre-swizzle + same XOR on
// the ds_read side) so the stride-128B ds_read_b128 frag reads are conflict-
// free. S^T = mfma(K, Q_scaled); per-lane online softmax (defer-max, THR=8);
// P bounced through wave-private LDS; O^T += mfma(V, P).
__global__ __launch_bounds__(512, 4) void k_attn(const bf16_t* __restrict__ Qb,
                                                 const bf16_t* __restrict__ Kb,
                                                 const bf16_t* __restrict__ Vt,
                                                 bf16_t* __restrict__ Ob) {
  __shared__ alignas(16) bf16_t Ks[2][64 * 64];   // 2 x 8KB
  __shared__ alignas(16) bf16_t Vs[2][64 * 64];   // 2 x 8KB
  __shared__ alignas(16) bf16_t P[8][16][72];     // per-wave, padded rows

  const int b0 = blockIdx.x;
  const int swz = (b0 & 7) * 64 + (b0 >> 3);      // 64 consecutive blocks/XCD
  const int qt = swz & 15, bh = swz >> 4;
  const int b = bh >> 4, h = bh & 15;
  const int t = threadIdx.x;
  const int w = t >> 6, lane = t & 63;
  const int l15 = lane & 15, g = lane >> 4;
  const bf16_t* Qp = Qb + bh * (NTOK * HD);
  const bf16_t* Kp = Kb + bh * (NTOK * HD);
  const bf16_t* Vp = Vt + bh * (NTOK * HD);
  const int q0 = qt * 128 + w * 16;

  // staging geometry: thread t -> LDS byte t*16 (linear, wavebase+lane*16);
  // logical (row, chunk) = (t>>3, t&7); source chunk pre-swizzled by row&7.
  const int sr = t >> 3, sc = t & 7;
  const int scs = ((sc ^ (sr & 7)) << 3);         // element offset in row
  const bf16_t* gK = Kp + sr * HD + scs;
  const bf16_t* gV = Vp + (long)sr * NTOK + scs;
  // frag-read swizzle: row = *16 + l15 so row&7 == l15&7
  const int cs0 = ((g ^ (l15 & 7)) << 4);         // byte offset, k-half 0
  const int cs1 = cs0 ^ 64;                       // k-half 1

  bf16x8 qfr[2];
#pragma unroll
  for (int kk = 0; kk < 2; ++kk)
    qfr[kk] = *(const bf16x8*)(Qp + (q0 + l15) * HD + kk * 32 + g * 8);

  const f32x4 vzero = {0.f, 0.f, 0.f, 0.f};
  f32x4 o[4];
#pragma unroll
  for (int df = 0; df < 4; ++df) o[df] = vzero;
  float m2 = -3.0e38f;
  float lsum = 0.f;

  // prologue: stage tile 0
  gload_lds16(gK, (char*)Ks[0] + t * 16);
  gload_lds16(gV, (char*)Vs[0] + t * 16);
  int cur = 0;

  for (int kt = 0; kt < NTOK; kt += 64) {
    __syncthreads();   // buf[cur] staged (vmcnt drained) + all waves done with buf[cur^1]
    if (kt + 64 < NTOK) {
      gload_lds16(gK + (kt + 64) * HD, (char*)Ks[cur ^ 1] + t * 16);
      gload_lds16(gV + (kt + 64),      (char*)Vs[cur ^ 1] + t * 16);
    }
    const char* kbuf = (const char*)Ks[cur];
    const char* vbuf = (const char*)Vs[cur];
    // ---- S^T = K * Q^T (rows = k-local, cols = q-local; pre-log2-scaled) ----
    f32x4 s[4];
#pragma unroll
    for (int kf = 0; kf < 4; ++kf) {
      int rb = (kf * 16 + l15) * 128;
      bf16x8 ka0 = *(const bf16x8*)(kbuf + rb + cs0);
      bf16x8 ka1 = *(const bf16x8*)(kbuf + rb + cs1);
      s[kf] = MFMA16(ka0, qfr[0], vzero);
      s[kf] = MFMA16(ka1, qfr[1], s[kf]);
    }
    // ---- online softmax for this lane's q-row (reduce over g via shfl) ----
    float mx = -3.0e38f;
#pragma unroll
    for (int kf = 0; kf < 4; ++kf)
#pragma unroll
      for (int r = 0; r < 4; ++r) mx = fmaxf(mx, s[kf][r]);
    mx = fmaxf(mx, __shfl_xor(mx, 16));
    mx = fmaxf(mx, __shfl_xor(mx, 32));
    if (__any(mx > m2 + 8.0f)) {     // defer-max (T13)
      float mn = fmaxf(m2, mx);
      float corr = exp2f(m2 - mn);
      m2 = mn;
      lsum *= corr;
#pragma unroll
      for (int df = 0; df < 4; ++df) o[df] *= corr;
    }
    float rs = 0.f;
#pragma unroll
    for (int kf = 0; kf < 4; ++kf) {
      float p0 = exp2f(s[kf][0] - m2);
      float p1 = exp2f(s[kf][1] - m2);
      float p2 = exp2f(s[kf][2] - m2);
      float p3 = exp2f(s[kf][3] - m2);
      rs += (p0 + p1) + (p2 + p3);
      bf16x4 pw;
      pw[0] = (bf16_t)p0; pw[1] = (bf16_t)p1; pw[2] = (bf16_t)p2; pw[3] = (bf16_t)p3;
      *(bf16x4*)&P[w][l15][kf * 16 + g * 4] = pw;
    }
    rs += __shfl_xor(rs, 16);
    rs += __shfl_xor(rs, 32);
    lsum += rs;
    // ---- O^T += V * P^T ----
#pragma unroll
    for (int kb = 0; kb < 2; ++kb) {
      bf16x8 pf = *(const bf16x8*)&P[w][l15][kb * 32 + g * 8];
      int csk = kb ? cs1 : cs0;
#pragma unroll
      for (int df = 0; df < 4; ++df) {
        bf16x8 va = *(const bf16x8*)(vbuf + (df * 16 + l15) * 128 + csk);
        o[df] = MFMA16(va, pf, o[df]);
      }
    }
    cur ^= 1;
  }
  // ---- normalize + write O[b][tok][h*64+d] (bf16, feeds proj GEMM) ----
  float inv = 1.0f / lsum;
  int tok = q0 + l15;
  bf16_t* op = Ob + (long)(b * NTOK + tok) * DIM + h * HD;
#pragma unroll
  for (int df = 0; df < 4; ++df) {
#pragma unroll
    for (int rp = 0; rp < 2; ++rp) {
      bf16x2 v2;
      v2[0] = (bf16_t)(o[df][rp * 2]     * inv);
      v2[1] = (bf16_t)(o[df][rp * 2 + 1] * inv);
      *(bf16x2*)(op + df * 16 + g * 4 + rp * 2) = v2;
    }
  }
}

// ---------------- GEMM2: out = O @ W_proj + b (fp32 out) ----------------
__global__ __launch_bounds__(256) void k_gemm_proj(const bf16_t* __restrict__ Ob,
                                                   const bf16_t* __restrict__ WpT,
                                                   const float* __restrict__ bp,
                                                   float* __restrict__ out) {
  __shared__ alignas(16) bf16_t As[128 * 32];
  __shared__ alignas(16) bf16_t Bs[128 * 32];
  f32x4 acc[4][4];
  const int bm = blockIdx.y * 128, bn = blockIdx.x * 128;
  gemm_core(Ob, WpT, DIM, bm, bn, As, Bs, acc);

  const int lane = threadIdx.x & 63, w = threadIdx.x >> 6;
  const int wr = (w >> 1) * 64, wc = (w & 1) * 64;
  const int l15 = lane & 15, g = lane >> 4;
#pragma unroll
  for (int n = 0; n < 4; ++n) {
    int col = bn + wc + n * 16 + l15;
    float bias = bp[col];
#pragma unroll
    for (int m = 0; m < 4; ++m) {
      int rowb = bm + wr + m * 16 + g * 4;
#pragma unroll
      for (int r = 0; r < 4; ++r)
        out[(long)(rowb + r) * DIM + col] = acc[m][n][r] + bias;
    }
  }
}

// ---------------------------------------------------------------------------
extern "C" void kernel_launch(void* const* d_in, const int* in_sizes, int n_in,
                              void* d_out, int out_size, void* d_ws, size_t ws_size,
                              hipStream_t stream) {
  const float* x     = (const float*)d_in[0];
  const float* Wqkv  = (const float*)d_in[1];
  const float* bqkv  = (const float*)d_in[2];
  const float* Wproj = (const float*)d_in[3];
  const float* bproj = (const float*)d_in[4];
  float* out = (float*)d_out;

  char* ws = (char*)d_ws;
  bf16_t* xb  = (bf16_t*)(ws);                    // 8 MB
  bf16_t* WqT = (bf16_t*)(ws + (8l  << 20));      // 6 MB
  bf16_t* WpT = (bf16_t*)(ws + (14l << 20));      // 2 MB
  bf16_t* Qb  = (bf16_t*)(ws + (16l << 20));      // 8 MB
  bf16_t* Kb  = (bf16_t*)(ws + (24l << 20));      // 8 MB
  bf16_t* Vt  = (bf16_t*)(ws + (32l << 20));      // 8 MB
  bf16_t* Ob  = (bf16_t*)(ws);                    // aliases xb (x dead after gemm_qkv)

  k_cvt<<<2048, 256, 0, stream>>>(x, xb);
  k_transpose_cvt<<<dim3(96, 32), 256, 0, stream>>>(Wqkv, WqT, 1024, 3072);
  k_transpose_cvt<<<dim3(32, 32), 256, 0, stream>>>(Wproj, WpT, 1024, 1024);
  k_gemm_qkv<<<dim3(24, 32), 256, 0, stream>>>(xb, WqT, bqkv, Qb, Kb, Vt);
  k_attn<<<512, 512, 0, stream>>>(Qb, Kb, Vt, Ob);
  k_gemm_proj<<<dim3(8, 32), 256, 0, stream>>>(Ob, WpT, bproj, out);
}